// Round 4
// baseline (373.463 us; speedup 1.0000x reference)
//
#include <hip/hip_runtime.h>
#include <hip/hip_bf16.h>
#include <stdint.h>

// MMD loss: L=8192 total rows, D=1024, n=4096 per half.
// result = (Sum_ss + Sum_tt - Sum_cross) / (5 n^2), bandwidth closed-form:
//   sum(d2) = 2L*sum(sq) - 2*||colsum||^2   (diagonal contributes exactly 0)
// 3 graph nodes: memset -> k_prep -> k_mmd (bw-reduce in block 0, finalize in
// last block via completion counter).

#define L_TOTAL 8192
#define D_FEAT  1024
#define N_HALF  4096
#define TILE    128
#define TTILES  64                      // L/TILE
#define NBLK    (TTILES*(TTILES+1)/2)   // 2080 lower-triangle tiles (2080%8==0)
#define BK      64                      // K-step: 128B rows -> full 8-slot swizzle
#define NT      (D_FEAT / BK)           // 16 K-steps

typedef __bf16 bf16_t;
typedef __bf16 bf16x4_t __attribute__((ext_vector_type(4)));
typedef __bf16 bf16x8_t __attribute__((ext_vector_type(8)));
typedef float  f32x4_t  __attribute__((ext_vector_type(4)));

// workspace layout (bytes)
#define XB_OFF   0                              // bf16 X [8192][1024] = 16 MB
#define SQ_OFF   (L_TOTAL * D_FEAT * 2)         // f32 sq[8192] (32 KB)
#define MS_OFF   (SQ_OFF + L_TOTAL * 4)         // memset-zeroed region:
#define SACC_OFF (MS_OFF)                       //   double S_acc
#define C1_OFF   (MS_OFF + 8)                   //   float c1 (0 until published)
#define CTR_OFF  (MS_OFF + 12)                  //   uint completion counter
#define COL_OFF  (MS_OFF + 16)                  //   f32 colsum[1024]
#define MS_BYTES (16 + D_FEAT * 4)

__device__ __forceinline__ void async_ld16(void* lds, const void* g) {
  auto ldsp = (__attribute__((address_space(3))) void*)(uintptr_t)lds;
  auto gp   = (const __attribute__((address_space(1))) void*)(uintptr_t)g;
  __builtin_amdgcn_global_load_lds(gp, ldsp, 16, 0, 0);  // lane i -> base + i*16
}

// --- kernel 1: cast to bf16 + per-row sum-of-squares (of the bf16-rounded
//     values, matching the Gram) + fp32 column-sum atomics (colsum pre-zeroed).
//     512 blocks x 256 threads; wave owns 4 rows; lane-contiguous float4s.
extern "C" __global__ __launch_bounds__(256) void k_prep(
    const float* __restrict__ src, const float* __restrict__ tgt,
    bf16_t* __restrict__ Xb, float* __restrict__ sq, float* __restrict__ colsum)
{
  __shared__ float cs[4][D_FEAT];               // per-wave colsum partials, 16KB
  const int tid  = threadIdx.x;
  const int lane = tid & 63;
  const int w    = tid >> 6;
  const int rbase = blockIdx.x * 16 + w * 4;

  float csp[16];
  #pragma unroll
  for (int j = 0; j < 16; ++j) csp[j] = 0.f;

  #pragma unroll
  for (int i = 0; i < 4; ++i) {
    const int row = rbase + i;
    const float* xr = (row < N_HALF) ? (src + (size_t)row * D_FEAT)
                                     : (tgt + (size_t)(row - N_HALF) * D_FEAT);
    float s = 0.f;
    #pragma unroll
    for (int q = 0; q < 4; ++q) {
      const float4 v = ((const float4*)xr)[q * 64 + lane];   // coalesced 16B/lane
      bf16x4_t bv;
      bv[0] = (bf16_t)v.x; bv[1] = (bf16_t)v.y; bv[2] = (bf16_t)v.z; bv[3] = (bf16_t)v.w;
      *(bf16x4_t*)(Xb + (size_t)row * D_FEAT + (q * 64 + lane) * 4) = bv;
      const float g0 = (float)bv[0], g1 = (float)bv[1], g2 = (float)bv[2], g3 = (float)bv[3];
      s += g0 * g0 + g1 * g1 + g2 * g2 + g3 * g3;
      csp[q * 4 + 0] += v.x; csp[q * 4 + 1] += v.y;
      csp[q * 4 + 2] += v.z; csp[q * 4 + 3] += v.w;
    }
    #pragma unroll
    for (int off = 32; off > 0; off >>= 1) s += __shfl_down(s, off);
    if (lane == 0) sq[row] = s;
  }

  #pragma unroll
  for (int q = 0; q < 4; ++q) {
    float4 v4 = make_float4(csp[q*4+0], csp[q*4+1], csp[q*4+2], csp[q*4+3]);
    *(float4*)&cs[w][(q * 64 + lane) * 4] = v4;
  }
  __syncthreads();
  #pragma unroll
  for (int k = 0; k < 4; ++k) {
    const int c = tid * 4 + k;
    atomicAdd(&colsum[c], cs[0][c] + cs[1][c] + cs[2][c] + cs[3][c]);
  }
}

// --- kernel 2: fused Gram-MFMA + RBF + signed reduction, lower-triangle tiles.
//     2-phase double-buffered pipeline (stage t+1 || compute t, one sync/iter).
//     Block 0 computes the bandwidth first and release-publishes c1; other
//     blocks acquire-spin at their epilogue (block 0 publishes far earlier).
//     Last block (completion counter) finalizes out[0].
extern "C" __global__ __launch_bounds__(256) void k_mmd(
    const bf16_t* __restrict__ Xb, const float* __restrict__ sq,
    const float* __restrict__ colsum, float* __restrict__ c1w,
    double* __restrict__ S_acc, unsigned* __restrict__ ctr,
    float* __restrict__ out)
{
  __shared__ __align__(16) bf16_t Abuf[2][TILE * BK];   // 2 x 16 KB
  __shared__ __align__(16) bf16_t Bbuf[2][TILE * BK];   // 2 x 16 KB

  const int tid  = threadIdx.x;
  const int lane = tid & 63;
  const int w    = tid >> 6;         // 4 waves, 2x2 over the 128x128 tile
  const int wr   = w >> 1, wc = w & 1;

  // ---- block 0: closed-form bandwidth -> publish c1 (before its main loop)
  float c1_local = 0.f;
  if (blockIdx.x == 0) {
    double t = 0.0;
    for (int i = tid; i < L_TOTAL; i += 256) t += (double)sq[i];
    t *= 2.0 * (double)L_TOTAL;
    double u = 0.0;
    #pragma unroll
    for (int k = 0; k < 4; ++k) { double v = colsum[tid * 4 + k]; u += v * v; }
    t -= 2.0 * u;
    double* red2 = (double*)Abuf;                 // 2 KB scratch, pre-staging
    red2[tid] = t;
    __syncthreads();
    for (int off = 128; off > 0; off >>= 1) {
      if (tid < off) red2[tid] += red2[tid + off];
      __syncthreads();
    }
    double bw = red2[0] / ((double)L_TOTAL * (double)L_TOTAL - (double)L_TOTAL);
    bw = bw / 4.0;                                // KERNEL_MUL ** (KERNEL_NUM//2)
    c1_local = (float)(-1.4426950408889634 / (16.0 * bw));
    if (tid == 0) {
      __hip_atomic_store((unsigned*)c1w, __builtin_bit_cast(unsigned, c1_local),
                         __ATOMIC_RELEASE, __HIP_MEMORY_SCOPE_AGENT);
    }
  }
  __syncthreads();   // block 0: red2 dead before staging; others: no-op cost

  // ---- tile decode + XCD-aware bijective swizzle (NBLK % 8 == 0)
  const int b = (blockIdx.x & 7) * (NBLK / 8) + (blockIdx.x >> 3);
  int ti = (int)((sqrtf(8.f * (float)b + 1.f) - 1.f) * 0.5f);
  while ((ti + 1) * (ti + 2) / 2 <= b) ++ti;
  while (ti * (ti + 1) / 2 > b) --ti;
  const int tj = b - ti * (ti + 1) / 2;          // tj <= ti
  const int row0 = ti * TILE, col0 = tj * TILE;

  // staging source offsets (elements), swizzle pre-permuted on the global side
  const int srow = lane >> 3;                    // 0..7
  const int scol = ((lane & 7) ^ srow) * 8;      // involution source column
  uint32_t offA[4], offB[4];
  #pragma unroll
  for (int q = 0; q < 4; ++q) {
    const int ch = w * 4 + q;
    offA[q] = (uint32_t)(row0 + ch * 8 + srow) * D_FEAT + scol;
    offB[q] = (uint32_t)(col0 + ch * 8 + srow) * D_FEAT + scol;
  }

  // fragment-read byte bases (XOR hoisted; kk=1 base = kk=0 base ^ 64)
  const int x = lane >> 4, y = lane & 7, rlo = lane & 15;
  const int baA0 = (wr * 64 + rlo) * (BK * 2) + ((x ^ y) * 16);
  const int baB0 = (wc * 64 + rlo) * (BK * 2) + ((x ^ y) * 16);

  f32x4_t acc[4][4] = {};            // wave computes 64x64 = 4x4 frags of 16x16

  auto stage = [&](bf16_t* Ad, bf16_t* Bd, int kt) {
    const int kofs = kt * BK;
    #pragma unroll
    for (int q = 0; q < 4; ++q) {
      async_ld16(&Ad[(w * 4 + q) * 512], Xb + offA[q] + kofs);
      async_ld16(&Bd[(w * 4 + q) * 512], Xb + offB[q] + kofs);
    }
  };
  auto compute = [&](const bf16_t* As, const bf16_t* Bs) {
    const char* Ac = (const char*)As;
    const char* Bc = (const char*)Bs;
    bf16x8_t af0[4], af1[4], bf0[4], bf1[4];
    #pragma unroll
    for (int m = 0; m < 4; ++m) {
      af0[m] = *(const bf16x8_t*)(Ac + (baA0 + m * 2048));
      af1[m] = *(const bf16x8_t*)(Ac + ((baA0 + m * 2048) ^ 64));
    }
    #pragma unroll
    for (int n = 0; n < 4; ++n) {
      bf0[n] = *(const bf16x8_t*)(Bc + (baB0 + n * 2048));
      bf1[n] = *(const bf16x8_t*)(Bc + ((baB0 + n * 2048) ^ 64));
    }
    #pragma unroll
    for (int m = 0; m < 4; ++m)
      #pragma unroll
      for (int n = 0; n < 4; ++n)
        acc[m][n] = __builtin_amdgcn_mfma_f32_16x16x32_bf16(af0[m], bf0[n], acc[m][n], 0, 0, 0);
    #pragma unroll
    for (int m = 0; m < 4; ++m)
      #pragma unroll
      for (int n = 0; n < 4; ++n)
        acc[m][n] = __builtin_amdgcn_mfma_f32_16x16x32_bf16(af1[m], bf1[n], acc[m][n], 0, 0, 0);
  };

  // ---- 2-phase pipeline: stage(t+1) issued before compute(t); 1 sync/iter
  stage(Abuf[0], Bbuf[0], 0);
  __syncthreads();                               // vmcnt(0) drain + barrier
  #pragma unroll 2
  for (int t = 0; t < NT; ++t) {
    const int cur = t & 1, nxt = cur ^ 1;        // compile-time under unroll 2
    if (t + 1 < NT) stage(Abuf[nxt], Bbuf[nxt], t + 1);
    compute(Abuf[cur], Bbuf[cur]);
    __syncthreads();                             // drain + all reads done
  }

  // ---- epilogue: get c1 (spin only if block 0 hasn't published — it has)
  float c1;
  if (blockIdx.x == 0) {
    c1 = c1_local;
  } else {
    unsigned v;
    while ((v = __hip_atomic_load((const unsigned*)c1w, __ATOMIC_ACQUIRE,
                                  __HIP_MEMORY_SCOPE_AGENT)) == 0u)
      __builtin_amdgcn_s_sleep(8);
    c1 = __builtin_bit_cast(float, v);           // c1 < 0 always => nonzero
  }

  const float sgn  = ((ti < TTILES / 2) == (tj < TTILES / 2)) ? 1.f : -1.f;
  const float wgt  = (ti == tj ? 1.f : 2.f) * sgn;
  float part = 0.f;
  const int colb = col0 + wc * 64 + rlo;
  const int rowb = row0 + wr * 64 + x * 4;   // C/D map: col=lane&15, row=(lane>>4)*4+reg
  #pragma unroll
  for (int m = 0; m < 4; ++m) {
    #pragma unroll
    for (int n = 0; n < 4; ++n) {
      const float sqj = sq[colb + n * 16];
      #pragma unroll
      for (int r = 0; r < 4; ++r) {
        const float sqi = sq[rowb + m * 16 + r];
        float d2 = fmaxf(sqi + sqj - 2.f * acc[m][n][r], 0.f);
        const float e  = __builtin_amdgcn_exp2f(d2 * c1);  // exp(-d2/(bw*16))
        const float e2 = e * e, e4 = e2 * e2, e8 = e4 * e4, e16 = e8 * e8;
        part += e + e2 + e4 + e8 + e16;
      }
    }
  }
  part *= wgt;

  #pragma unroll
  for (int off = 32; off > 0; off >>= 1) part += __shfl_down(part, off);
  float* red = (float*)Abuf;                 // LDS dead past the loop
  __syncthreads();
  if (lane == 0) red[w] = part;
  __syncthreads();
  if (tid == 0) {
    atomicAdd(S_acc, (double)(red[0] + red[1] + red[2] + red[3]));
    __threadfence();
    const unsigned old = atomicAdd(ctr, 1u);
    if (old == NBLK - 1) {                   // last block: finalize
      __threadfence();
      const double S = atomicAdd(S_acc, 0.0);
      out[0] = (float)(S / (5.0 * (double)N_HALF * (double)N_HALF));
    }
  }
}

extern "C" void kernel_launch(void* const* d_in, const int* in_sizes, int n_in,
                              void* d_out, int out_size, void* d_ws, size_t ws_size,
                              hipStream_t stream) {
  const float* src = (const float*)d_in[0];
  const float* tgt = (const float*)d_in[1];
  float* out = (float*)d_out;
  char* ws = (char*)d_ws;
  bf16_t*   Xb     = (bf16_t*)(ws + XB_OFF);
  float*    sq     = (float*)(ws + SQ_OFF);
  double*   S_acc  = (double*)(ws + SACC_OFF);
  float*    c1w    = (float*)(ws + C1_OFF);
  unsigned* ctr    = (unsigned*)(ws + CTR_OFF);
  float*    colsum = (float*)(ws + COL_OFF);

  hipMemsetAsync(ws + MS_OFF, 0, MS_BYTES, stream);
  k_prep<<<512, 256, 0, stream>>>(src, tgt, Xb, sq, colsum);
  k_mmd <<<NBLK, 256, 0, stream>>>(Xb, sq, colsum, c1w, S_acc, ctr, out);
}

// Round 5
// 328.424 us; speedup vs baseline: 1.1371x; 1.1371x over previous
//
#include <hip/hip_runtime.h>
#include <hip/hip_bf16.h>
#include <stdint.h>

// MMD loss: L=8192 total rows, D=1024, n=4096 per half.
// result = (Sum_ss + Sum_tt - Sum_cross) / (5 n^2), bandwidth closed-form:
//   sum(d2) = 2L*sum(sq) - 2*||colsum||^2   (diagonal contributes exactly 0)
// 3 graph nodes: memset -> k_prep -> k_mmd (bw-reduce in block 0, finalize in
// last block via completion counter).
// k_mmd: 32 KB single-buffer LDS (4 blocks/CU co-residency = the m114 implicit
// overlap; 64 KB dbuf was a 2x regression), phase-split k-step so stage(t+1)
// flies under the second half's 16 MFMAs.

#define L_TOTAL 8192
#define D_FEAT  1024
#define N_HALF  4096
#define TILE    128
#define TTILES  64                      // L/TILE
#define NBLK    (TTILES*(TTILES+1)/2)   // 2080 lower-triangle tiles (2080%8==0)
#define BK      64                      // K-step: 128B rows -> full 8-slot swizzle
#define NT      (D_FEAT / BK)           // 16 K-steps
#define REPL    16                      // colsum replicas (contention killer)

typedef __bf16 bf16_t;
typedef __bf16 bf16x4_t __attribute__((ext_vector_type(4)));
typedef __bf16 bf16x8_t __attribute__((ext_vector_type(8)));
typedef float  f32x4_t  __attribute__((ext_vector_type(4)));

// workspace layout (bytes)
#define XB_OFF   0                              // bf16 X [8192][1024] = 16 MB
#define SQ_OFF   (L_TOTAL * D_FEAT * 2)         // f32 sq[8192] (32 KB)
#define MS_OFF   (SQ_OFF + L_TOTAL * 4)         // memset-zeroed region:
#define SACC_OFF (MS_OFF)                       //   double S_acc
#define C1_OFF   (MS_OFF + 8)                   //   float c1 (0 until published)
#define CTR_OFF  (MS_OFF + 12)                  //   uint completion counter
#define COL_OFF  (MS_OFF + 16)                  //   f32 colsum[REPL][1024]
#define MS_BYTES (16 + REPL * D_FEAT * 4)

__device__ __forceinline__ void async_ld16(void* lds, const void* g) {
  auto ldsp = (__attribute__((address_space(3))) void*)(uintptr_t)lds;
  auto gp   = (const __attribute__((address_space(1))) void*)(uintptr_t)g;
  __builtin_amdgcn_global_load_lds(gp, ldsp, 16, 0, 0);  // lane i -> base + i*16
}

// --- kernel 1: cast to bf16 + per-row sum-of-squares (of the bf16-rounded
//     values, matching the Gram) + fp32 column sums into 16 replicas
//     (32 serialized RMWs/address instead of 512).
extern "C" __global__ __launch_bounds__(256) void k_prep(
    const float* __restrict__ src, const float* __restrict__ tgt,
    bf16_t* __restrict__ Xb, float* __restrict__ sq, float* __restrict__ colsum)
{
  __shared__ float cs[4][D_FEAT];               // per-wave colsum partials, 16KB
  const int tid  = threadIdx.x;
  const int lane = tid & 63;
  const int w    = tid >> 6;
  const int rbase = blockIdx.x * 16 + w * 4;

  float csp[16];
  #pragma unroll
  for (int j = 0; j < 16; ++j) csp[j] = 0.f;

  #pragma unroll
  for (int i = 0; i < 4; ++i) {
    const int row = rbase + i;
    const float* xr = (row < N_HALF) ? (src + (size_t)row * D_FEAT)
                                     : (tgt + (size_t)(row - N_HALF) * D_FEAT);
    float s = 0.f;
    #pragma unroll
    for (int q = 0; q < 4; ++q) {
      const float4 v = ((const float4*)xr)[q * 64 + lane];   // coalesced 16B/lane
      bf16x4_t bv;
      bv[0] = (bf16_t)v.x; bv[1] = (bf16_t)v.y; bv[2] = (bf16_t)v.z; bv[3] = (bf16_t)v.w;
      *(bf16x4_t*)(Xb + (size_t)row * D_FEAT + (q * 64 + lane) * 4) = bv;
      const float g0 = (float)bv[0], g1 = (float)bv[1], g2 = (float)bv[2], g3 = (float)bv[3];
      s += g0 * g0 + g1 * g1 + g2 * g2 + g3 * g3;
      csp[q * 4 + 0] += v.x; csp[q * 4 + 1] += v.y;
      csp[q * 4 + 2] += v.z; csp[q * 4 + 3] += v.w;
    }
    #pragma unroll
    for (int off = 32; off > 0; off >>= 1) s += __shfl_down(s, off);
    if (lane == 0) sq[row] = s;
  }

  #pragma unroll
  for (int q = 0; q < 4; ++q) {
    float4 v4 = make_float4(csp[q*4+0], csp[q*4+1], csp[q*4+2], csp[q*4+3]);
    *(float4*)&cs[w][(q * 64 + lane) * 4] = v4;
  }
  __syncthreads();
  float* crep = colsum + (blockIdx.x & (REPL - 1)) * D_FEAT;
  #pragma unroll
  for (int k = 0; k < 4; ++k) {
    const int c = tid * 4 + k;
    atomicAdd(&crep[c], cs[0][c] + cs[1][c] + cs[2][c] + cs[3][c]);
  }
}

// --- kernel 2: fused Gram-MFMA + RBF + signed reduction, lower-triangle tiles.
extern "C" __global__ __launch_bounds__(256) void k_mmd(
    const bf16_t* __restrict__ Xb, const float* __restrict__ sq,
    const float* __restrict__ colsum, float* __restrict__ c1w,
    double* __restrict__ S_acc, unsigned* __restrict__ ctr,
    float* __restrict__ out)
{
  __shared__ __align__(16) bf16_t As[TILE * BK];   // 16 KB
  __shared__ __align__(16) bf16_t Bs[TILE * BK];   // 16 KB

  const int tid  = threadIdx.x;
  const int lane = tid & 63;
  const int w    = tid >> 6;         // 4 waves, 2x2 over the 128x128 tile
  const int wr   = w >> 1, wc = w & 1;

  // ---- block 0 prework: reduce colsum replicas + closed-form bw -> publish c1
  float c1_local = 0.f;
  if (blockIdx.x == 0) {
    double t = 0.0;
    for (int i = tid; i < L_TOTAL; i += 256) t += (double)sq[i];
    t *= 2.0 * (double)L_TOTAL;
    double u = 0.0;
    #pragma unroll
    for (int k = 0; k < 4; ++k) {
      const int c = tid * 4 + k;
      float csum = 0.f;
      #pragma unroll
      for (int r = 0; r < REPL; ++r) csum += colsum[r * D_FEAT + c];
      u += (double)csum * (double)csum;
    }
    t -= 2.0 * u;
    double* red2 = (double*)As;                   // 2 KB scratch, pre-staging
    red2[tid] = t;
    __syncthreads();
    for (int off = 128; off > 0; off >>= 1) {
      if (tid < off) red2[tid] += red2[tid + off];
      __syncthreads();
    }
    double bw = red2[0] / ((double)L_TOTAL * (double)L_TOTAL - (double)L_TOTAL);
    bw = bw / 4.0;                                // KERNEL_MUL ** (KERNEL_NUM//2)
    c1_local = (float)(-1.4426950408889634 / (16.0 * bw));
    if (tid == 0) {
      __hip_atomic_store((unsigned*)c1w, __builtin_bit_cast(unsigned, c1_local),
                         __ATOMIC_RELEASE, __HIP_MEMORY_SCOPE_AGENT);
    }
  }
  __syncthreads();   // uniform across blocks; block 0: red2 dead before staging

  // ---- tile decode + XCD-aware bijective swizzle (NBLK % 8 == 0)
  const int b = (blockIdx.x & 7) * (NBLK / 8) + (blockIdx.x >> 3);
  int ti = (int)((sqrtf(8.f * (float)b + 1.f) - 1.f) * 0.5f);
  while ((ti + 1) * (ti + 2) / 2 <= b) ++ti;
  while (ti * (ti + 1) / 2 > b) --ti;
  const int tj = b - ti * (ti + 1) / 2;          // tj <= ti
  const int row0 = ti * TILE, col0 = tj * TILE;

  // staging source offsets (elements), swizzle pre-permuted on the global side
  const int srow = lane >> 3;                    // 0..7
  const int scol = ((lane & 7) ^ srow) * 8;      // involution source column
  uint32_t offA[4], offB[4];
  #pragma unroll
  for (int q = 0; q < 4; ++q) {
    const int ch = w * 4 + q;
    offA[q] = (uint32_t)(row0 + ch * 8 + srow) * D_FEAT + scol;
    offB[q] = (uint32_t)(col0 + ch * 8 + srow) * D_FEAT + scol;
  }

  // fragment-read byte bases (XOR hoisted; k-half-1 base = base ^ 64)
  const int x = lane >> 4, y = lane & 7, rlo = lane & 15;
  const int baA0 = (wr * 64 + rlo) * (BK * 2) + ((x ^ y) * 16);
  const int baB0 = (wc * 64 + rlo) * (BK * 2) + ((x ^ y) * 16);
  const char* Ac = (const char*)As;
  const char* Bc = (const char*)Bs;

  f32x4_t acc[4][4] = {};            // wave computes 64x64 = 4x4 frags of 16x16

  auto stage = [&](int kt) {
    const int kofs = kt * BK;
    #pragma unroll
    for (int q = 0; q < 4; ++q) {
      async_ld16(&As[(w * 4 + q) * 512], Xb + offA[q] + kofs);
      async_ld16(&Bs[(w * 4 + q) * 512], Xb + offB[q] + kofs);
    }
  };

  // ---- main loop: single buffer, phase-split k-step.
  //  read half-0 frags -> 16 MFMA -> read half-1 frags -> barrier (tile-t reads
  //  done) -> stage(t+1) same buffer -> 16 MFMA (covers load flight) ->
  //  barrier+vmcnt(0) (tile t+1 visible).
  stage(0);
  __syncthreads();
  for (int t = 0; t < NT; ++t) {
    bf16x8_t fa[4], fb[4];
    #pragma unroll
    for (int m = 0; m < 4; ++m) fa[m] = *(const bf16x8_t*)(Ac + baA0 + m * 2048);
    #pragma unroll
    for (int n = 0; n < 4; ++n) fb[n] = *(const bf16x8_t*)(Bc + baB0 + n * 2048);
    #pragma unroll
    for (int m = 0; m < 4; ++m)
      #pragma unroll
      for (int n = 0; n < 4; ++n)
        acc[m][n] = __builtin_amdgcn_mfma_f32_16x16x32_bf16(fa[m], fb[n], acc[m][n], 0, 0, 0);
    #pragma unroll
    for (int m = 0; m < 4; ++m) fa[m] = *(const bf16x8_t*)(Ac + (baA0 ^ 64) + m * 2048);
    #pragma unroll
    for (int n = 0; n < 4; ++n) fb[n] = *(const bf16x8_t*)(Bc + (baB0 ^ 64) + n * 2048);
    __syncthreads();                             // all LDS reads of tile t done
    if (t + 1 < NT) stage(t + 1);                // loads fly under the MFMAs
    #pragma unroll
    for (int m = 0; m < 4; ++m)
      #pragma unroll
      for (int n = 0; n < 4; ++n)
        acc[m][n] = __builtin_amdgcn_mfma_f32_16x16x32_bf16(fa[m], fb[n], acc[m][n], 0, 0, 0);
    __syncthreads();                             // vmcnt(0): tile t+1 visible
  }

  // ---- epilogue: get c1 (block 0 published it long before any epilogue)
  float c1;
  if (blockIdx.x == 0) {
    c1 = c1_local;
  } else {
    unsigned v;
    while ((v = __hip_atomic_load((const unsigned*)c1w, __ATOMIC_ACQUIRE,
                                  __HIP_MEMORY_SCOPE_AGENT)) == 0u)
      __builtin_amdgcn_s_sleep(8);
    c1 = __builtin_bit_cast(float, v);           // c1 < 0 always => nonzero
  }

  const float sgn  = ((ti < TTILES / 2) == (tj < TTILES / 2)) ? 1.f : -1.f;
  const float wgt  = (ti == tj ? 1.f : 2.f) * sgn;
  float part = 0.f;
  const int colb = col0 + wc * 64 + rlo;
  const int rowb = row0 + wr * 64 + x * 4;   // C/D map: col=lane&15, row=(lane>>4)*4+reg
  #pragma unroll
  for (int m = 0; m < 4; ++m) {
    #pragma unroll
    for (int n = 0; n < 4; ++n) {
      const float sqj = sq[colb + n * 16];
      #pragma unroll
      for (int r = 0; r < 4; ++r) {
        const float sqi = sq[rowb + m * 16 + r];
        float d2 = fmaxf(sqi + sqj - 2.f * acc[m][n][r], 0.f);
        const float e  = __builtin_amdgcn_exp2f(d2 * c1);  // exp(-d2/(bw*16))
        const float e2 = e * e, e4 = e2 * e2, e8 = e4 * e4, e16 = e8 * e8;
        part += e + e2 + e4 + e8 + e16;
      }
    }
  }
  part *= wgt;

  #pragma unroll
  for (int off = 32; off > 0; off >>= 1) part += __shfl_down(part, off);
  float* red = (float*)As;                   // LDS dead past the loop
  __syncthreads();
  if (lane == 0) red[w] = part;
  __syncthreads();
  if (tid == 0) {
    atomicAdd(S_acc, (double)(red[0] + red[1] + red[2] + red[3]));
    __threadfence();
    const unsigned old = atomicAdd(ctr, 1u);
    if (old == NBLK - 1) {                   // last block: finalize
      __threadfence();
      const double S = atomicAdd(S_acc, 0.0);
      out[0] = (float)(S / (5.0 * (double)N_HALF * (double)N_HALF));
    }
  }
}

extern "C" void kernel_launch(void* const* d_in, const int* in_sizes, int n_in,
                              void* d_out, int out_size, void* d_ws, size_t ws_size,
                              hipStream_t stream) {
  const float* src = (const float*)d_in[0];
  const float* tgt = (const float*)d_in[1];
  float* out = (float*)d_out;
  char* ws = (char*)d_ws;
  bf16_t*   Xb     = (bf16_t*)(ws + XB_OFF);
  float*    sq     = (float*)(ws + SQ_OFF);
  double*   S_acc  = (double*)(ws + SACC_OFF);
  float*    c1w    = (float*)(ws + C1_OFF);
  unsigned* ctr    = (unsigned*)(ws + CTR_OFF);
  float*    colsum = (float*)(ws + COL_OFF);

  hipMemsetAsync(ws + MS_OFF, 0, MS_BYTES, stream);
  k_prep<<<512, 256, 0, stream>>>(src, tgt, Xb, sq, colsum);
  k_mmd <<<NBLK, 256, 0, stream>>>(Xb, sq, colsum, c1w, S_acc, ctr, out);
}

// Round 7
// 189.818 us; speedup vs baseline: 1.9675x; 1.7302x over previous
//
#include <hip/hip_runtime.h>
#include <hip/hip_bf16.h>
#include <stdint.h>

// MMD loss: L=8192 total rows, D=1024, n=4096 per half.
// result = (Sum_ss + Sum_tt - Sum_cross) / (5 n^2), bandwidth closed-form:
//   sum(d2) = 2L*sum(sq) - 2*||colsum||^2   (diagonal contributes exactly 0)
// Structure = round-1 empirical best (BK=32, 16KB LDS, 2-barrier k-step,
// separate small kernels) + ONE change: rotation swizzle (phys slot =
// (s + (r>>1)) & 3) kills the measured 8-way ds_read conflict at zero cost.

#define L_TOTAL 8192
#define D_FEAT  1024
#define N_HALF  4096
#define TILE    128
#define TTILES  64                      // L/TILE
#define NBLK    (TTILES*(TTILES+1)/2)   // 2080 lower-triangle tiles (2080%8==0)
#define BK      32                      // K-step: 64B rows, 4x16B slots
#define REPL    16                      // colsum replicas (atomic contention)

typedef __bf16 bf16_t;
typedef __bf16 bf16x4_t __attribute__((ext_vector_type(4)));
typedef __bf16 bf16x8_t __attribute__((ext_vector_type(8)));
typedef float  f32x4_t  __attribute__((ext_vector_type(4)));

// workspace layout (bytes)
#define XB_OFF   0                              // bf16 X [8192][1024] = 16 MB
#define SQ_OFF   (L_TOTAL * D_FEAT * 2)         // f32 sq[8192] (32 KB)
#define MS_OFF   (SQ_OFF + L_TOTAL * 4)         // memset-zeroed region:
#define SACC_OFF (MS_OFF)                       //   double S_acc
#define COL_OFF  (MS_OFF + 8)                   //   f32 colsum[REPL][1024]
#define MS_BYTES (8 + REPL * D_FEAT * 4)
#define C1_OFF   (MS_OFF + MS_BYTES)            // float c1 (k_bw writes)

__device__ __forceinline__ void async_ld16(void* lds, const void* g) {
  auto ldsp = (__attribute__((address_space(3))) void*)(uintptr_t)lds;
  auto gp   = (const __attribute__((address_space(1))) void*)(uintptr_t)g;
  __builtin_amdgcn_global_load_lds(gp, ldsp, 16, 0, 0);  // lane i -> base + i*16
}

// --- kernel 1: cast to bf16 + per-row sum-of-squares (of the bf16-rounded
//     values, matching the Gram) + fp32 column sums into 16 replicas.
extern "C" __global__ __launch_bounds__(256) void k_prep(
    const float* __restrict__ src, const float* __restrict__ tgt,
    bf16_t* __restrict__ Xb, float* __restrict__ sq, float* __restrict__ colsum)
{
  __shared__ float cs[4][D_FEAT];               // per-wave colsum partials, 16KB
  const int tid  = threadIdx.x;
  const int lane = tid & 63;
  const int w    = tid >> 6;
  const int rbase = blockIdx.x * 16 + w * 4;

  float csp[16];
  #pragma unroll
  for (int j = 0; j < 16; ++j) csp[j] = 0.f;

  #pragma unroll
  for (int i = 0; i < 4; ++i) {
    const int row = rbase + i;
    const float* xr = (row < N_HALF) ? (src + (size_t)row * D_FEAT)
                                     : (tgt + (size_t)(row - N_HALF) * D_FEAT);
    float s = 0.f;
    #pragma unroll
    for (int q = 0; q < 4; ++q) {
      const float4 v = ((const float4*)xr)[q * 64 + lane];   // coalesced 16B/lane
      bf16x4_t bv;
      bv[0] = (bf16_t)v.x; bv[1] = (bf16_t)v.y; bv[2] = (bf16_t)v.z; bv[3] = (bf16_t)v.w;
      *(bf16x4_t*)(Xb + (size_t)row * D_FEAT + (q * 64 + lane) * 4) = bv;
      const float g0 = (float)bv[0], g1 = (float)bv[1], g2 = (float)bv[2], g3 = (float)bv[3];
      s += g0 * g0 + g1 * g1 + g2 * g2 + g3 * g3;
      csp[q * 4 + 0] += v.x; csp[q * 4 + 1] += v.y;
      csp[q * 4 + 2] += v.z; csp[q * 4 + 3] += v.w;
    }
    #pragma unroll
    for (int off = 32; off > 0; off >>= 1) s += __shfl_down(s, off);
    if (lane == 0) sq[row] = s;
  }

  #pragma unroll
  for (int q = 0; q < 4; ++q) {
    float4 v4 = make_float4(csp[q*4+0], csp[q*4+1], csp[q*4+2], csp[q*4+3]);
    *(float4*)&cs[w][(q * 64 + lane) * 4] = v4;
  }
  __syncthreads();
  float* crep = colsum + (blockIdx.x & (REPL - 1)) * D_FEAT;
  #pragma unroll
  for (int k = 0; k < 4; ++k) {
    const int c = tid * 4 + k;
    atomicAdd(&crep[c], cs[0][c] + cs[1][c] + cs[2][c] + cs[3][c]);
  }
}

// --- kernel 2: c1 = -log2(e)/(16*bw),  bw = (sum(d2)/(L^2-L)) / 4
extern "C" __global__ __launch_bounds__(1024) void k_bw(
    const float* __restrict__ sq, const float* __restrict__ colsum,
    float* __restrict__ c1out)
{
  const int tid = threadIdx.x;
  double t = 0.0;
  for (int i = tid; i < L_TOTAL; i += 1024) t += (double)sq[i];
  t *= 2.0 * (double)L_TOTAL;
  if (tid < D_FEAT) {
    float csum = 0.f;
    #pragma unroll
    for (int r = 0; r < REPL; ++r) csum += colsum[r * D_FEAT + tid];
    t -= 2.0 * (double)csum * (double)csum;
  }
  __shared__ double red[1024];
  red[tid] = t;
  __syncthreads();
  for (int off = 512; off > 0; off >>= 1) {
    if (tid < off) red[tid] += red[tid + off];
    __syncthreads();
  }
  if (tid == 0) {
    double bw = red[0] / ((double)L_TOTAL * (double)L_TOTAL - (double)L_TOTAL);
    bw = bw / 4.0;                               // KERNEL_MUL ** (KERNEL_NUM//2)
    *c1out = (float)(-1.4426950408889634 / (16.0 * bw));
  }
}

// --- kernel 3: fused Gram-MFMA + RBF + signed reduction, lower-triangle tiles.
//     Rotation swizzle: phys slot p of row r holds global slot (p-(r>>1))&3;
//     reader uses p=(s+(r>>1))&3. 16 frag-read lanes hit all 8 bank-quads
//     exactly twice (2-way = free, m136). Lane-constant -> fully hoisted.
extern "C" __global__ __launch_bounds__(256) void k_mmd(
    const bf16_t* __restrict__ Xb, const float* __restrict__ sq,
    const float* __restrict__ c1ptr, double* __restrict__ S_acc)
{
  __shared__ __align__(16) bf16_t As[TILE * BK];   // 8 KB
  __shared__ __align__(16) bf16_t Bs[TILE * BK];   // 8 KB

  // XCD-aware bijective swizzle (NBLK % 8 == 0)
  const int b = (blockIdx.x & 7) * (NBLK / 8) + (blockIdx.x >> 3);
  int ti = (int)((sqrtf(8.f * (float)b + 1.f) - 1.f) * 0.5f);
  while ((ti + 1) * (ti + 2) / 2 <= b) ++ti;
  while (ti * (ti + 1) / 2 > b) --ti;
  const int tj = b - ti * (ti + 1) / 2;          // tj <= ti
  const int row0 = ti * TILE, col0 = tj * TILE;

  const int tid  = threadIdx.x;
  const int lane = tid & 63;
  const int w    = tid >> 6;         // 4 waves, 2x2 over the 128x128 tile
  const int wr   = w >> 1, wc = w & 1;

  f32x4_t acc[4][4] = {};            // wave computes 64x64 = 4x4 frags of 16x16

  // staging: chunk ch covers 16 rows x 32 elems (1024 B). lane i -> row i>>2,
  // phys slot i&3; source col = global slot ((i&3)-(i>>3))&3 (pre-rotated).
  const int srow = lane >> 2;                          // 0..15
  const int scol = (((lane & 3) - (lane >> 3)) & 3) * 8;
  uint32_t offA[2], offB[2];
  #pragma unroll
  for (int q = 0; q < 2; ++q) {
    const int ch = w * 2 + q;
    offA[q] = (uint32_t)(row0 + ch * 16 + srow) * D_FEAT + scol;
    offB[q] = (uint32_t)(col0 + ch * 16 + srow) * D_FEAT + scol;
  }

  // frag-read byte bases: global slot s = lane>>4 of row r at phys
  // p = (s + (r>>1)) & 3; in-loop offset m*1024 only.
  const int rlo = lane & 15, x = lane >> 4;
  const int p   = (x + (rlo >> 1)) & 3;                // lane-constant
  const int baA = (wr * 64 + rlo) * (BK * 2) + p * 16;
  const int baB = (wc * 64 + rlo) * (BK * 2) + p * 16;
  const char* Ac = (const char*)As;
  const char* Bc = (const char*)Bs;

  for (int k0 = 0; k0 < D_FEAT; k0 += BK) {
    #pragma unroll
    for (int q = 0; q < 2; ++q) {
      async_ld16(&As[(w * 2 + q) * 512], Xb + offA[q] + k0);
      async_ld16(&Bs[(w * 2 + q) * 512], Xb + offB[q] + k0);
    }
    __syncthreads();                 // drains vmcnt -> tiles visible

    bf16x8_t af[4], bfr[4];
    #pragma unroll
    for (int m = 0; m < 4; ++m) af[m]  = *(const bf16x8_t*)(Ac + baA + m * 1024);
    #pragma unroll
    for (int n = 0; n < 4; ++n) bfr[n] = *(const bf16x8_t*)(Bc + baB + n * 1024);

    #pragma unroll
    for (int m = 0; m < 4; ++m)
      #pragma unroll
      for (int n = 0; n < 4; ++n)
        acc[m][n] = __builtin_amdgcn_mfma_f32_16x16x32_bf16(af[m], bfr[n], acc[m][n], 0, 0, 0);
    __syncthreads();
  }

  // epilogue: d2 -> 5-scale RBF via 1 exp2 + 4 squarings; signed partial sum
  const float c1   = *c1ptr;                      // -log2e/(16*bw)
  const float sgn  = ((ti < TTILES / 2) == (tj < TTILES / 2)) ? 1.f : -1.f;
  const float wgt  = (ti == tj ? 1.f : 2.f) * sgn;
  float part = 0.f;
  const int colb = col0 + wc * 64 + rlo;
  const int rowb = row0 + wr * 64 + x * 4;   // C/D map: col=lane&15, row=(lane>>4)*4+reg
  #pragma unroll
  for (int m = 0; m < 4; ++m) {
    #pragma unroll
    for (int n = 0; n < 4; ++n) {
      const float sqj = sq[colb + n * 16];
      #pragma unroll
      for (int r = 0; r < 4; ++r) {
        const float sqi = sq[rowb + m * 16 + r];
        float d2 = fmaxf(sqi + sqj - 2.f * acc[m][n][r], 0.f);
        const float e  = __builtin_amdgcn_exp2f(d2 * c1);  // exp(-d2/(bw*16))
        const float e2 = e * e, e4 = e2 * e2, e8 = e4 * e4, e16 = e8 * e8;
        part += e + e2 + e4 + e8 + e16;
      }
    }
  }
  part *= wgt;

  #pragma unroll
  for (int off = 32; off > 0; off >>= 1) part += __shfl_down(part, off);
  float* red = (float*)As;                   // LDS dead past the loop
  __syncthreads();
  if (lane == 0) red[w] = part;
  __syncthreads();
  if (tid == 0)
    atomicAdd(S_acc, (double)(red[0] + red[1] + red[2] + red[3]));
}

// --- kernel 4: finalize
extern "C" __global__ void k_fin(const double* __restrict__ S_acc, float* __restrict__ out)
{
  out[0] = (float)(*S_acc / (5.0 * (double)N_HALF * (double)N_HALF));
}

extern "C" void kernel_launch(void* const* d_in, const int* in_sizes, int n_in,
                              void* d_out, int out_size, void* d_ws, size_t ws_size,
                              hipStream_t stream) {
  const float* src = (const float*)d_in[0];
  const float* tgt = (const float*)d_in[1];
  float* out = (float*)d_out;
  char* ws = (char*)d_ws;
  bf16_t* Xb     = (bf16_t*)(ws + XB_OFF);
  float*  sq     = (float*)(ws + SQ_OFF);
  double* S_acc  = (double*)(ws + SACC_OFF);
  float*  colsum = (float*)(ws + COL_OFF);
  float*  c1     = (float*)(ws + C1_OFF);

  hipMemsetAsync(ws + MS_OFF, 0, MS_BYTES, stream);
  k_prep<<<512, 256, 0, stream>>>(src, tgt, Xb, sq, colsum);
  k_bw  <<<1, 1024, 0, stream>>>(sq, colsum, c1);
  k_mmd <<<NBLK, 256, 0, stream>>>(Xb, sq, c1, S_acc);
  k_fin <<<1, 1, 0, stream>>>(S_acc, out);
}